// Round 7
// baseline (561.893 us; speedup 1.0000x reference)
//
#include <hip/hip_runtime.h>
#include <hip/hip_bf16.h>

typedef __attribute__((ext_vector_type(8))) short bf16x8;
typedef __attribute__((ext_vector_type(4))) float f32x4;

#define NE 8192
#define MT 32
#define DD 256
#define NAPP 262144
#define NSLOT (NE*MT)
#define NSYM 50000
#define NSYMP 50048
#define TPB 16   // tiles per persistent block in k_gate1

// ws layout (bytes)
#define WS_WINNER 0
#define WS_WTSW   (1u<<20)
#define WS_WTLIN  (2u<<20)
#define WS_SYMGC  (3u<<20)   // NSYMP*512*2B = 51.2MB

static __device__ __forceinline__ unsigned short f2b(float x){
  union{float f; unsigned u;} v; v.f = x;
  unsigned r = (v.u + 0x7fffu + ((v.u>>16)&1u))>>16;
  return (unsigned short)r;
}
static __device__ __forceinline__ unsigned pk2(float a, float b){
  return (unsigned)f2b(a) | ((unsigned)f2b(b)<<16);
}
static __device__ __forceinline__ float frombf(unsigned short u){ union{unsigned x; float f;} v; v.x = ((unsigned)u)<<16; return v.f; }

static __device__ __forceinline__ void gload16(const void* g, void* l){
  __builtin_amdgcn_global_load_lds((const __attribute__((address_space(1))) void*)g,
                                   (__attribute__((address_space(3))) void*)l, 16, 0, 0);
}

static __device__ __forceinline__ bf16x8 cvt8(float4 q0, float4 q1){
  union { unsigned u[4]; bf16x8 v; } r;
  union { __hip_bfloat162 h; unsigned u; } c;
  c.h = __float22bfloat162_rn(float2{q0.x, q0.y}); r.u[0] = c.u;
  c.h = __float22bfloat162_rn(float2{q0.z, q0.w}); r.u[1] = c.u;
  c.h = __float22bfloat162_rn(float2{q1.x, q1.y}); r.u[2] = c.u;
  c.h = __float22bfloat162_rn(float2{q1.z, q1.w}); r.u[3] = c.u;
  return r.v;
}

// ---- K0: weights f32 [512][256] -> bf16 transposed, two copies (pre-swizzled + linear)
__global__ void k_wt(const float* __restrict__ w0, const float* __restrict__ w1,
                     const float* __restrict__ w2, const float* __restrict__ w3,
                     char* __restrict__ wtsw, unsigned short* __restrict__ wtlin){
  int g = blockIdx.x*256 + threadIdx.x;   // m(2) kg(6) n(8)
  int m = g >> 14;
  int kg = (g >> 8) & 63;
  int n = g & 255;
  const float* W = (m==0)?w0:(m==1)?w1:(m==2)?w2:w3;
  unsigned short v[8];
  #pragma unroll
  for (int i=0;i<8;i++) v[i] = f2b(W[(kg*8+i)*DD + n]);
  uint4 u;
  u.x = (unsigned)v[0] | ((unsigned)v[1]<<16);
  u.y = (unsigned)v[2] | ((unsigned)v[3]<<16);
  u.z = (unsigned)v[4] | ((unsigned)v[5]<<16);
  u.w = (unsigned)v[6] | ((unsigned)v[7]<<16);
  *(uint4*)(wtlin + (size_t)m*131072 + n*512 + kg*8) = u;
  int rot = ((kg & 3) + (n >> 1)) & 3;
  *(uint4*)(wtsw + (size_t)m*262144 + n*1024 + (kg>>2)*64 + rot*16) = u;
}

// ---- K1: last-write-wins winner per slot
__global__ void k_winner(const int* __restrict__ ei, const int* __restrict__ ti,
                         int* __restrict__ winner){
  int i = blockIdx.x*256 + threadIdx.x;
  atomicMax(&winner[ei[i]*MT + ti[i]], i);
}

// ---- K_syms: SymGC[s] = sym[s] @ [Wg1_bot | Wc1_bot] (bf16), interleaved so gate1
// reads {g0,c0,g1,c1} for its (wv,l15) as one ushort4. (validated R6)
__global__ __launch_bounds__(512, 4)
void k_syms(const float* __restrict__ sym, const char* __restrict__ wtsw,
            unsigned short* __restrict__ symgc){
  __shared__ char Abuf[32768];
  __shared__ char Bbuf[32768];

  int tid = threadIdx.x, lane = tid & 63, wv = tid >> 6;
  int l15 = lane & 15, lg = lane >> 4;
  int wq = wv & 3; bool isC = wv >= 4;
  int s0 = blockIdx.x * 64;

  {
    int r = tid >> 3;
    int row = s0 + r;
    char* arow = Abuf + r*512;
    unsigned swz = (unsigned)((r & 15) << 4);
    if (row < NSYM){
      const float* src = sym + (size_t)row*DD;
      #pragma unroll
      for (int i=0;i<4;i++){
        int c = (tid & 7) + i*8;
        float4 x = *(const float4*)(src + c*8);
        float4 y = *(const float4*)(src + c*8 + 4);
        uint4 u; u.x=pk2(x.x,x.y); u.y=pk2(x.z,x.w); u.z=pk2(y.x,y.y); u.w=pk2(y.z,y.w);
        *(uint4*)(arow + ((c*16) ^ swz)) = u;
      }
    } else {
      uint4 u = {0,0,0,0};
      #pragma unroll
      for (int i=0;i<4;i++){
        int c = (tid & 7) + i*8;
        *(uint4*)(arow + ((c*16) ^ swz)) = u;
      }
    }
  }
  __syncthreads();

  f32x4 acc[4][4];
  f32x4 zz = {0.f,0.f,0.f,0.f};
  #pragma unroll
  for (int rt=0;rt<4;rt++)
    #pragma unroll
    for (int ct=0;ct<4;ct++) acc[rt][ct]=zz;

  const char* wbG = wtsw;
  const char* wbC = wtsw + 262144;

  for (int kt=0; kt<8; ++kt){
    __syncthreads();
    #pragma unroll
    for (int i=0;i<4;i++){
      int n = wv*64 + i*16 + (lane>>2);
      const char* src = ((n < 256)? wbG : wbC) + (size_t)(n & 255)*1024 + (8+kt)*64 + (lane&3)*16;
      gload16(src, Bbuf + n*64 + (lane&3)*16);
    }
    __syncthreads();
    int koff = kt*64 + lg*16;
    bf16x8 a[4], b[4];
    #pragma unroll
    for (int rt=0;rt<4;rt++)
      a[rt] = *(const bf16x8*)(Abuf + (rt*16 + l15)*512 + (koff ^ (l15<<4)));
    #pragma unroll
    for (int ct=0;ct<4;ct++){
      int nn = (isC?256:0) + wq*64 + ct*16 + l15;
      b[ct] = *(const bf16x8*)(Bbuf + nn*64 + (((lg + (nn>>1)) & 3)<<4));
    }
    #pragma unroll
    for (int rt=0;rt<4;rt++)
      #pragma unroll
      for (int ct=0;ct<4;ct++)
        acc[rt][ct] = __builtin_amdgcn_mfma_f32_16x16x32_bf16(a[rt], b[ct], acc[rt][ct], 0,0,0);
  }

  #pragma unroll
  for (int rt=0;rt<4;rt++)
    #pragma unroll
    for (int ct=0;ct<4;ct++)
      #pragma unroll
      for (int j=0;j<4;j++){
        int row = s0 + rt*16 + lg*4 + j;
        int idx = (wq*2 + (ct>>1))*64 + l15*4 + (ct&1)*2 + (isC?1:0);
        symgc[(size_t)row*512 + idx] = f2b(acc[rt][ct][j]);
      }
}

// ---- K2: gate1, persistent blocks. 256 blocks x 16 tiles; 8 waves/block.
// B panel (both matrices, K=256) held in 128 VGPRs per lane, loaded ONCE.
// A tile = raw f32 in LDS (2 x 64KB dbuf) via global_load_lds with source-side
// chunk-XOR (^ row&14, even mask) for conflict-free b128 reads. One barrier/tile.
__global__ __launch_bounds__(512, 2)
void k_gate1(const float* __restrict__ expr, const unsigned short* __restrict__ wtlin,
             const float* __restrict__ bg, const float* __restrict__ bc,
             const int* __restrict__ winner, const int* __restrict__ appsym,
             const unsigned short* __restrict__ symgc,
             float* __restrict__ outcomb){
  __shared__ float Af[2][64][256];   // 128 KB

  int tid = threadIdx.x, lane = tid & 63, wv = tid >> 6;
  int l15 = lane & 15, lg = lane >> 4;

  // ---- B panel into registers: breg[mat][ct][ks], col = wv*32 + ct*16 + l15
  bf16x8 breg[2][2][8];
  #pragma unroll
  for (int mat=0; mat<2; ++mat)
    #pragma unroll
    for (int ct=0; ct<2; ++ct){
      const unsigned short* wp = wtlin + (size_t)mat*131072
                               + (size_t)(wv*32 + ct*16 + l15)*512 + lg*8;
      #pragma unroll
      for (int ks=0; ks<8; ++ks)
        breg[mat][ct][ks] = *(const bf16x8*)(wp + ks*32);
    }
  float bgv[2], bcv[2];
  #pragma unroll
  for (int ct=0; ct<2; ++ct){
    int c = wv*32 + ct*16 + l15;
    bgv[ct] = bg[c]; bcv[ct] = bc[c];
  }

  int base = blockIdx.x * TPB;

  // ---- prologue: stage tile 0 into buf 0
  {
    int s0 = base*64;
    #pragma unroll
    for (int i=0;i<8;i++){
      int r = wv*8 + i;
      const float* src = expr + (size_t)(s0 + r)*DD + ((lane ^ (r & 14))<<2);
      gload16(src, (char*)&Af[0][r][0] + lane*16);
    }
  }
  __syncthreads();

  for (int t=0; t<TPB; ++t){
    int cur = t & 1;
    int s0 = (base + t)*64;

    int wn = winner[s0 + lane];
    int sidv = (wn >= 0) ? appsym[wn] : 0;
    unsigned long long hwmask = __ballot(wn >= 0);

    if (t < TPB-1){
      int s1 = s0 + 64;
      #pragma unroll
      for (int i=0;i<8;i++){
        int r = wv*8 + i;
        const float* src = expr + (size_t)(s1 + r)*DD + ((lane ^ (r & 14))<<2);
        gload16(src, (char*)&Af[cur^1][r][0] + lane*16);
      }
    }

    f32x4 acc[2][4][2];
    f32x4 zz = {0.f,0.f,0.f,0.f};
    #pragma unroll
    for (int m=0;m<2;m++)
      #pragma unroll
      for (int rt=0;rt<4;rt++){ acc[m][rt][0]=zz; acc[m][rt][1]=zz; }

    #pragma unroll
    for (int ks=0; ks<8; ++ks){
      bf16x8 a[4];
      #pragma unroll
      for (int rt=0;rt<4;rt++){
        int row = rt*16 + l15;
        int c = ks*8 + lg*2;
        const char* p = (const char*)&Af[cur][row][0] + ((c ^ (row & 14))<<4);
        float4 q0 = *(const float4*)p;
        float4 q1 = *(const float4*)(p + 16);
        a[rt] = cvt8(q0, q1);
      }
      #pragma unroll
      for (int rt=0;rt<4;rt++){
        #pragma unroll
        for (int ct=0;ct<2;ct++){
          acc[0][rt][ct] = __builtin_amdgcn_mfma_f32_16x16x32_bf16(a[rt], breg[0][ct][ks], acc[0][rt][ct], 0,0,0);
          acc[1][rt][ct] = __builtin_amdgcn_mfma_f32_16x16x32_bf16(a[rt], breg[1][ct][ks], acc[1][rt][ct], 0,0,0);
        }
      }
    }

    // epilogue: gate combine (prev exact f32 from LDS) + token-mean
    float osum[2][2] = {{0.f,0.f},{0.f,0.f}};
    #pragma unroll
    for (int rt=0;rt<4;rt++){
      #pragma unroll
      for (int j=0;j<4;j++){
        int row = rt*16 + lg*4 + j;
        int sid = __shfl(sidv, row);
        const ushort4 sv = *(const ushort4*)(symgc + (size_t)sid*512 + wv*64 + l15*4);
        bool hw = (hwmask >> row) & 1ull;
        #pragma unroll
        for (int ct=0;ct<2;ct++){
          int col = wv*32 + ct*16 + l15;
          float p = Af[cur][row][(((col>>2) ^ (row & 14))<<2) + (col & 3)];
          float gl = acc[0][rt][ct][j] + frombf(sv.x*(ct==0)+sv.z*(ct==1)) + bgv[ct];
          float cl = acc[1][rt][ct][j] + frombf(sv.y*(ct==0)+sv.w*(ct==1)) + bcv[ct];
          float f = 1.f/(1.f + __expf(-gl));
          float cd = fmaxf(cl, 0.f);
          osum[rt>>1][ct] += hw ? (f*p + (1.f-f)*cd) : p;
        }
      }
    }
    #pragma unroll
    for (int e=0;e<2;e++)
      #pragma unroll
      for (int ct=0;ct<2;ct++){
        float s = osum[e][ct];
        s += __shfl_xor(s, 16);
        s += __shfl_xor(s, 32);
        if (lane < 16)
          outcomb[(size_t)((base+t)*2 + e)*DD + wv*32 + ct*16 + l15] = s * (1.f/32.f);
      }
    __syncthreads();
  }
}

// ---- K3: gate2 over 64 expressions per block, in-place on d_out (validated; uses wt_lin)
__global__ __launch_bounds__(1024)
void k_gate2(const float* __restrict__ prevn, const float* comb,
             const float* __restrict__ bg, const float* __restrict__ bc,
             const unsigned short* __restrict__ Wgt, const unsigned short* __restrict__ Wct,
             float* out){
  __shared__ char A[64*1024];

  int tid  = threadIdx.x;
  int lane = tid & 63;
  int wv   = tid >> 6;
  int wr = wv >> 3, wc = wv & 7;
  int l15 = lane & 15, lg = lane >> 4;
  int e0 = blockIdx.x * 64;

  {
    int row = tid >> 4, cb = (tid & 15)*16;
    unsigned swz = (unsigned)((row&7)<<4);
    const float* src = prevn + (size_t)(e0+row)*DD + cb;
    const float* s2  = comb  + (size_t)(e0+row)*DD + cb;
    char* arow = A + row*1024;
    #pragma unroll
    for (int i=0;i<2;i++){
      float4 x = *(const float4*)(src + i*8);
      float4 y = *(const float4*)(src + i*8 + 4);
      uint4 u; u.x=pk2(x.x,x.y); u.y=pk2(x.z,x.w); u.z=pk2(y.x,y.y); u.w=pk2(y.z,y.w);
      *(uint4*)(arow + (((cb+i*8)*2) ^ swz)) = u;
    }
    #pragma unroll
    for (int i=0;i<2;i++){
      float4 x = *(const float4*)(s2 + i*8);
      float4 y = *(const float4*)(s2 + i*8 + 4);
      uint4 u; u.x=pk2(x.x,x.y); u.y=pk2(x.z,x.w); u.z=pk2(y.x,y.y); u.w=pk2(y.z,y.w);
      *(uint4*)(arow + (((256+cb+i*8)*2) ^ swz)) = u;
    }
  }
  __syncthreads();

  unsigned swzL = (unsigned)((l15&7)<<4);
  const char* pa0 = A + (wr*32 + l15)*1024;
  const char* pa1 = pa0 + 16*1024;
  const unsigned short* wg0 = Wgt + (size_t)(wc*32 + l15)*512 + lg*8;
  const unsigned short* wc0 = Wct + (size_t)(wc*32 + l15)*512 + lg*8;

  f32x4 accg[2][2], accc[2][2];
  f32x4 zz = {0.f,0.f,0.f,0.f};
  #pragma unroll
  for (int ri=0;ri<2;ri++){ accg[ri][0]=zz; accg[ri][1]=zz; accc[ri][0]=zz; accc[ri][1]=zz; }

  for (int ks=0; ks<16; ++ks){
    int koff = (ks*64 + lg*16) ^ (int)swzL;
    bf16x8 a0 = *(const bf16x8*)(pa0 + koff);
    bf16x8 a1 = *(const bf16x8*)(pa1 + koff);
    int kw = ks*32;
    #pragma unroll
    for (int ct=0; ct<2; ++ct){
      bf16x8 b = *(const bf16x8*)(wg0 + ct*16*512 + kw);
      accg[0][ct] = __builtin_amdgcn_mfma_f32_16x16x32_bf16(a0, b, accg[0][ct], 0,0,0);
      accg[1][ct] = __builtin_amdgcn_mfma_f32_16x16x32_bf16(a1, b, accg[1][ct], 0,0,0);
    }
  }

  float bgv[2], bcv[2];
  #pragma unroll
  for (int ct=0;ct<2;ct++){ int c = wc*32+ct*16+l15; bgv[ct]=bg[c]; bcv[ct]=bc[c]; }
  #pragma unroll
  for (int ri=0;ri<2;ri++)
    #pragma unroll
    for (int ct=0;ct<2;ct++)
      #pragma unroll
      for (int j=0;j<4;j++)
        accg[ri][ct][j] = 1.f/(1.f + __expf(-(accg[ri][ct][j] + bgv[ct])));

  for (int ks=0; ks<16; ++ks){
    int koff = (ks*64 + lg*16) ^ (int)swzL;
    bf16x8 a0 = *(const bf16x8*)(pa0 + koff);
    bf16x8 a1 = *(const bf16x8*)(pa1 + koff);
    int kw = ks*32;
    #pragma unroll
    for (int ct=0; ct<2; ++ct){
      bf16x8 b = *(const bf16x8*)(wc0 + ct*16*512 + kw);
      accc[0][ct] = __builtin_amdgcn_mfma_f32_16x16x32_bf16(a0, b, accc[0][ct], 0,0,0);
      accc[1][ct] = __builtin_amdgcn_mfma_f32_16x16x32_bf16(a1, b, accc[1][ct], 0,0,0);
    }
  }

  #pragma unroll
  for (int ct=0; ct<2; ++ct){
    #pragma unroll
    for (int ri=0; ri<2; ++ri){
      #pragma unroll
      for (int j=0;j<4;j++){
        int row = wr*32 + ri*16 + lg*4 + j;
        int col = wc*32 + ct*16 + l15;
        int e = e0 + row;
        float prevv = prevn[(size_t)e*DD + col];
        float fr = accg[ri][ct][j];
        float cand = fmaxf(accc[ri][ct][j] + bcv[ct], 0.f);
        out[(size_t)e*DD + col] = fr*prevv + (1.f-fr)*cand;
      }
    }
  }
}

extern "C" void kernel_launch(void* const* d_in, const int* in_sizes, int n_in,
                              void* d_out, int out_size, void* d_ws, size_t ws_size,
                              hipStream_t stream){
  const float* expr = (const float*)d_in[0];
  const float* sym  = (const float*)d_in[1];
  const float* prevn= (const float*)d_in[2];
  const float* Wg1 = (const float*)d_in[3];
  const float* bg1 = (const float*)d_in[4];
  const float* Wc1 = (const float*)d_in[5];
  const float* bc1 = (const float*)d_in[6];
  const float* Wg2 = (const float*)d_in[7];
  const float* bg2 = (const float*)d_in[8];
  const float* Wc2 = (const float*)d_in[9];
  const float* bc2 = (const float*)d_in[10];
  const int* aei = (const int*)d_in[11];
  const int* ati = (const int*)d_in[12];
  const int* asi = (const int*)d_in[13];
  float* outp = (float*)d_out;

  char* wsb = (char*)d_ws;
  int* winner = (int*)(wsb + WS_WINNER);
  char* wtsw = wsb + WS_WTSW;
  unsigned short* wtlin = (unsigned short*)(wsb + WS_WTLIN);
  unsigned short* symgc = (unsigned short*)(wsb + WS_SYMGC);

  hipMemsetAsync(winner, 0xFF, NSLOT*sizeof(int), stream);
  k_wt<<<256, 256, 0, stream>>>(Wg1, Wc1, Wg2, Wc2, wtsw, wtlin);
  k_winner<<<NAPP/256, 256, 0, stream>>>(aei, ati, winner);
  k_syms<<<NSYMP/64, 512, 0, stream>>>(sym, wtsw, symgc);
  k_gate1<<<NSLOT/(64*TPB), 512, 0, stream>>>(expr, wtlin, bg1, bc1, winner, asi, symgc, outp);
  k_gate2<<<NE/64, 1024, 0, stream>>>(prevn, outp, bg2, bc2,
                                      wtlin + 262144, wtlin + 393216, outp);
}

// Round 8
// 318.396 us; speedup vs baseline: 1.7648x; 1.7648x over previous
//
#include <hip/hip_runtime.h>
#include <hip/hip_bf16.h>

typedef __attribute__((ext_vector_type(8))) short bf16x8;
typedef __attribute__((ext_vector_type(4))) float f32x4;

#define NE 8192
#define MT 32
#define DD 256
#define NAPP 262144
#define NSLOT (NE*MT)
#define NSYM 50000
#define NSYMP 50048

// ws layout (bytes)
#define WS_WINNER 0
#define WS_WTSW   (1u<<20)
#define WS_WTLIN  (2u<<20)
#define WS_SYMGC  (3u<<20)   // NSYMP*512*2B = 51.2MB

static __device__ __forceinline__ unsigned short f2b(float x){
  union{float f; unsigned u;} v; v.f = x;
  unsigned r = (v.u + 0x7fffu + ((v.u>>16)&1u))>>16;
  return (unsigned short)r;
}
static __device__ __forceinline__ unsigned pk2(float a, float b){
  return (unsigned)f2b(a) | ((unsigned)f2b(b)<<16);
}
static __device__ __forceinline__ float frombf(unsigned short u){ union{unsigned x; float f;} v; v.x = ((unsigned)u)<<16; return v.f; }

static __device__ __forceinline__ void gload16(const void* g, void* l){
  __builtin_amdgcn_global_load_lds((const __attribute__((address_space(1))) void*)g,
                                   (__attribute__((address_space(3))) void*)l, 16, 0, 0);
}

#define ASM_BAR()  asm volatile("s_barrier" ::: "memory")
#define WAITV2()   asm volatile("s_waitcnt vmcnt(2)" ::: "memory")
#define WAITV0()   asm volatile("s_waitcnt vmcnt(0)" ::: "memory")
#define WAITL()    asm volatile("s_waitcnt lgkmcnt(0)" ::: "memory")

// ---- K0: weights f32 [512][256] -> bf16 transposed, two copies (pre-swizzled + linear)
__global__ void k_wt(const float* __restrict__ w0, const float* __restrict__ w1,
                     const float* __restrict__ w2, const float* __restrict__ w3,
                     char* __restrict__ wtsw, unsigned short* __restrict__ wtlin){
  int g = blockIdx.x*256 + threadIdx.x;   // m(2) kg(6) n(8)
  int m = g >> 14;
  int kg = (g >> 8) & 63;
  int n = g & 255;
  const float* W = (m==0)?w0:(m==1)?w1:(m==2)?w2:w3;
  unsigned short v[8];
  #pragma unroll
  for (int i=0;i<8;i++) v[i] = f2b(W[(kg*8+i)*DD + n]);
  uint4 u;
  u.x = (unsigned)v[0] | ((unsigned)v[1]<<16);
  u.y = (unsigned)v[2] | ((unsigned)v[3]<<16);
  u.z = (unsigned)v[4] | ((unsigned)v[5]<<16);
  u.w = (unsigned)v[6] | ((unsigned)v[7]<<16);
  *(uint4*)(wtlin + (size_t)m*131072 + n*512 + kg*8) = u;
  int rot = ((kg & 3) + (n >> 1)) & 3;
  *(uint4*)(wtsw + (size_t)m*262144 + n*1024 + (kg>>2)*64 + rot*16) = u;
}

// ---- K1: last-write-wins winner per slot
__global__ void k_winner(const int* __restrict__ ei, const int* __restrict__ ti,
                         int* __restrict__ winner){
  int i = blockIdx.x*256 + threadIdx.x;
  atomicMax(&winner[ei[i]*MT + ti[i]], i);
}

// ---- K_syms: SymGC[s] = sym[s] @ [Wg1_bot | Wc1_bot] (bf16), interleaved (validated R6)
__global__ __launch_bounds__(512, 4)
void k_syms(const float* __restrict__ sym, const char* __restrict__ wtsw,
            unsigned short* __restrict__ symgc){
  __shared__ char Abuf[32768];
  __shared__ char Bbuf[32768];

  int tid = threadIdx.x, lane = tid & 63, wv = tid >> 6;
  int l15 = lane & 15, lg = lane >> 4;
  int wq = wv & 3; bool isC = wv >= 4;
  int s0 = blockIdx.x * 64;

  {
    int r = tid >> 3;
    int row = s0 + r;
    char* arow = Abuf + r*512;
    unsigned swz = (unsigned)((r & 15) << 4);
    if (row < NSYM){
      const float* src = sym + (size_t)row*DD;
      #pragma unroll
      for (int i=0;i<4;i++){
        int c = (tid & 7) + i*8;
        float4 x = *(const float4*)(src + c*8);
        float4 y = *(const float4*)(src + c*8 + 4);
        uint4 u; u.x=pk2(x.x,x.y); u.y=pk2(x.z,x.w); u.z=pk2(y.x,y.y); u.w=pk2(y.z,y.w);
        *(uint4*)(arow + ((c*16) ^ swz)) = u;
      }
    } else {
      uint4 u = {0,0,0,0};
      #pragma unroll
      for (int i=0;i<4;i++){
        int c = (tid & 7) + i*8;
        *(uint4*)(arow + ((c*16) ^ swz)) = u;
      }
    }
  }
  __syncthreads();

  f32x4 acc[4][4];
  f32x4 zz = {0.f,0.f,0.f,0.f};
  #pragma unroll
  for (int rt=0;rt<4;rt++)
    #pragma unroll
    for (int ct=0;ct<4;ct++) acc[rt][ct]=zz;

  const char* wbG = wtsw;
  const char* wbC = wtsw + 262144;

  for (int kt=0; kt<8; ++kt){
    __syncthreads();
    #pragma unroll
    for (int i=0;i<4;i++){
      int n = wv*64 + i*16 + (lane>>2);
      const char* src = ((n < 256)? wbG : wbC) + (size_t)(n & 255)*1024 + (8+kt)*64 + (lane&3)*16;
      gload16(src, Bbuf + n*64 + (lane&3)*16);
    }
    __syncthreads();
    int koff = kt*64 + lg*16;
    bf16x8 a[4], b[4];
    #pragma unroll
    for (int rt=0;rt<4;rt++)
      a[rt] = *(const bf16x8*)(Abuf + (rt*16 + l15)*512 + (koff ^ (l15<<4)));
    #pragma unroll
    for (int ct=0;ct<4;ct++){
      int nn = (isC?256:0) + wq*64 + ct*16 + l15;
      b[ct] = *(const bf16x8*)(Bbuf + nn*64 + (((lg + (nn>>1)) & 3)<<4));
    }
    #pragma unroll
    for (int rt=0;rt<4;rt++)
      #pragma unroll
      for (int ct=0;ct<4;ct++)
        acc[rt][ct] = __builtin_amdgcn_mfma_f32_16x16x32_bf16(a[rt], b[ct], acc[rt][ct], 0,0,0);
  }

  #pragma unroll
  for (int rt=0;rt<4;rt++)
    #pragma unroll
    for (int ct=0;ct<4;ct++)
      #pragma unroll
      for (int j=0;j<4;j++){
        int row = s0 + rt*16 + lg*4 + j;
        int idx = (wq*2 + (ct>>1))*64 + l15*4 + (ct&1)*2 + (isC?1:0);
        symgc[(size_t)row*512 + idx] = f2b(acc[rt][ct][j]);
      }
}

// ---- K2: gate1 with T3+T4 counted-vmcnt pipeline.
// 4096 blocks x 512 thr (8 waves). A [64][K=256] bf16 in LDS (32KB, staged once).
// B: 16 slabs (BK=32 x one matrix, 16KB each) through a 3-slot LDS ring via
// global_load_lds; phase p issues slab p+2; phase end = vmcnt(2) + raw s_barrier
// (vmcnt(0) only at the tail). 8 MFMA per phase wrapped in setprio(1).
__global__ __launch_bounds__(512, 4)
void k_gate1(const float* __restrict__ expr, const char* __restrict__ wtsw,
             const float* __restrict__ bg, const float* __restrict__ bc,
             const int* __restrict__ winner, const int* __restrict__ appsym,
             const unsigned short* __restrict__ symgc,
             float* __restrict__ outcomb){
  __shared__ char Abuf[32768];
  __shared__ char Bb[3*16384];

  int tid = threadIdx.x, lane = tid & 63, wv = tid >> 6;
  int l15 = lane & 15, lg = lane >> 4;
  int s0 = blockIdx.x * 64;

  // stage slab s (mat = s&1, k-slab = s>>1) into ring slot s%3.
  // dest is tid-linear*16 => wave-uniform base + lane*16 (gload_lds requirement).
  auto issue = [&](int s){
    const char* wm = wtsw + (size_t)(s & 1)*262144 + (s >> 1)*64;
    char* dst = Bb + (s % 3)*16384;
    #pragma unroll
    for (int i=0;i<2;i++){
      int g = tid + i*512;
      gload16(wm + (size_t)(g>>2)*1024 + (g&3)*16, dst + g*16);
    }
  };

  issue(0); issue(1);

  { // stage A = orig expr [64][256] bf16, chunk ^ ((row&15)<<4)  (validated R5)
    int r = tid >> 3;
    const float* src = expr + (size_t)(s0 + r)*DD;
    char* arow = Abuf + r*512;
    unsigned swz = (unsigned)((r & 15) << 4);
    #pragma unroll
    for (int i=0;i<4;i++){
      int c = (tid & 7) + i*8;
      float4 x = *(const float4*)(src + c*8);
      float4 y = *(const float4*)(src + c*8 + 4);
      uint4 u; u.x=pk2(x.x,x.y); u.y=pk2(x.z,x.w); u.z=pk2(y.x,y.y); u.w=pk2(y.z,y.w);
      *(uint4*)(arow + ((c*16) ^ swz)) = u;
    }
  }

  int wn = winner[s0 + lane];
  int sidv = (wn >= 0) ? appsym[wn] : 0;
  unsigned long long hwmask = __ballot(wn >= 0);

  float bgv[2], bcv[2];
  #pragma unroll
  for (int ct=0; ct<2; ++ct){
    int c = wv*32 + ct*16 + l15;
    bgv[ct] = bg[c]; bcv[ct] = bc[c];
  }

  WAITV2();   // slab0 landed (A/winner loads already drained by their uses)
  WAITL();    // A ds_writes visible
  ASM_BAR();

  f32x4 accG[4][2], accC[4][2];
  f32x4 zz = {0.f,0.f,0.f,0.f};
  #pragma unroll
  for (int rt=0;rt<4;rt++){ accG[rt][0]=zz; accG[rt][1]=zz; accC[rt][0]=zz; accC[rt][1]=zz; }

  int nn0 = wv*32 + l15;
  int boff = nn0*64 + (((lg + (nn0>>1)) & 3) << 4);   // ct=1 col is +16 rows => +1024, same rot

  #pragma unroll
  for (int kt=0; kt<8; ++kt){
    const int sG = 2*kt, sC = 2*kt+1;
    bf16x8 a[4];
    // ---------------- G phase (slab sG) ----------------
    if (sG + 2 < 16) issue(sG + 2);
    {
      int koff = (kt*64 + lg*16) ^ (l15 << 4);
      #pragma unroll
      for (int rt=0; rt<4; ++rt)
        a[rt] = *(const bf16x8*)(Abuf + (rt*16 + l15)*512 + koff);
    }
    bf16x8 b0, b1;
    {
      const char* base = Bb + (sG % 3)*16384 + boff;
      b0 = *(const bf16x8*)(base);
      b1 = *(const bf16x8*)(base + 1024);
    }
    ASM_BAR();
    WAITL();
    __builtin_amdgcn_s_setprio(1);
    #pragma unroll
    for (int rt=0; rt<4; ++rt){
      accG[rt][0] = __builtin_amdgcn_mfma_f32_16x16x32_bf16(a[rt], b0, accG[rt][0], 0,0,0);
      accG[rt][1] = __builtin_amdgcn_mfma_f32_16x16x32_bf16(a[rt], b1, accG[rt][1], 0,0,0);
    }
    __builtin_amdgcn_s_setprio(0);
    if (sG <= 13) { WAITV2(); } else { WAITV0(); }
    ASM_BAR();
    // ---------------- C phase (slab sC) ----------------
    if (sC + 2 < 16) issue(sC + 2);
    {
      const char* base = Bb + (sC % 3)*16384 + boff;
      b0 = *(const bf16x8*)(base);
      b1 = *(const bf16x8*)(base + 1024);
    }
    ASM_BAR();
    WAITL();
    __builtin_amdgcn_s_setprio(1);
    #pragma unroll
    for (int rt=0; rt<4; ++rt){
      accC[rt][0] = __builtin_amdgcn_mfma_f32_16x16x32_bf16(a[rt], b0, accC[rt][0], 0,0,0);
      accC[rt][1] = __builtin_amdgcn_mfma_f32_16x16x32_bf16(a[rt], b1, accC[rt][1], 0,0,0);
    }
    __builtin_amdgcn_s_setprio(0);
    if (sC <= 13) { WAITV2(); ASM_BAR(); }
    else if (sC == 14) { WAITV0(); ASM_BAR(); }
    // sC == 15: done, fall through to epilogue
  }

  // ---- epilogue: in-register combine + token-mean (prev = exact f32, L1/L2-warm)
  float osum[2][2] = {{0.f,0.f},{0.f,0.f}};
  #pragma unroll
  for (int rt=0;rt<4;rt++){
    #pragma unroll
    for (int j=0;j<4;j++){
      int row = rt*16 + lg*4 + j;
      int sid = __shfl(sidv, row);
      const ushort4 sv = *(const ushort4*)(symgc + (size_t)sid*512 + wv*64 + l15*4);
      bool hw = (hwmask >> row) & 1ull;
      const float* prow = expr + (size_t)(s0+row)*DD;
      #pragma unroll
      for (int ct=0;ct<2;ct++){
        float p = prow[wv*32 + ct*16 + l15];
        float gl = accG[rt][ct][j] + frombf(ct ? sv.z : sv.x) + bgv[ct];
        float cl = accC[rt][ct][j] + frombf(ct ? sv.w : sv.y) + bcv[ct];
        float f = 1.f/(1.f + __expf(-gl));
        float cd = fmaxf(cl, 0.f);
        osum[rt>>1][ct] += hw ? (f*p + (1.f-f)*cd) : p;
      }
    }
  }
  #pragma unroll
  for (int e=0;e<2;e++)
    #pragma unroll
    for (int ct=0;ct<2;ct++){
      float s = osum[e][ct];
      s += __shfl_xor(s, 16);
      s += __shfl_xor(s, 32);
      if (lane < 16)
        outcomb[(size_t)(blockIdx.x*2 + e)*DD + wv*32 + ct*16 + l15] = s * (1.f/32.f);
    }
}

// ---- K3: gate2 over 64 expressions per block, in-place on d_out (validated; uses wt_lin)
__global__ __launch_bounds__(1024)
void k_gate2(const float* __restrict__ prevn, const float* comb,
             const float* __restrict__ bg, const float* __restrict__ bc,
             const unsigned short* __restrict__ Wgt, const unsigned short* __restrict__ Wct,
             float* out){
  __shared__ char A[64*1024];

  int tid  = threadIdx.x;
  int lane = tid & 63;
  int wv   = tid >> 6;
  int wr = wv >> 3, wc = wv & 7;
  int l15 = lane & 15, lg = lane >> 4;
  int e0 = blockIdx.x * 64;

  {
    int row = tid >> 4, cb = (tid & 15)*16;
    unsigned swz = (unsigned)((row&7)<<4);
    const float* src = prevn + (size_t)(e0+row)*DD + cb;
    const float* s2  = comb  + (size_t)(e0+row)*DD + cb;
    char* arow = A + row*1024;
    #pragma unroll
    for (int i=0;i<2;i++){
      float4 x = *(const float4*)(src + i*8);
      float4 y = *(const float4*)(src + i*8 + 4);
      uint4 u; u.x=pk2(x.x,x.y); u.y=pk2(x.z,x.w); u.z=pk2(y.x,y.y); u.w=pk2(y.z,y.w);
      *(uint4*)(arow + (((cb+i*8)*2) ^ swz)) = u;
    }
    #pragma unroll
    for (int i=0;i<2;i++){
      float4 x = *(const float4*)(s2 + i*8);
      float4 y = *(const float4*)(s2 + i*8 + 4);
      uint4 u; u.x=pk2(x.x,x.y); u.y=pk2(x.z,x.w); u.z=pk2(y.x,y.y); u.w=pk2(y.z,y.w);
      *(uint4*)(arow + (((256+cb+i*8)*2) ^ swz)) = u;
    }
  }
  __syncthreads();

  unsigned swzL = (unsigned)((l15&7)<<4);
  const char* pa0 = A + (wr*32 + l15)*1024;
  const char* pa1 = pa0 + 16*1024;
  const unsigned short* wg0 = Wgt + (size_t)(wc*32 + l15)*512 + lg*8;
  const unsigned short* wc0 = Wct + (size_t)(wc*32 + l15)*512 + lg*8;

  f32x4 accg[2][2], accc[2][2];
  f32x4 zz = {0.f,0.f,0.f,0.f};
  #pragma unroll
  for (int ri=0;ri<2;ri++){ accg[ri][0]=zz; accg[ri][1]=zz; accc[ri][0]=zz; accc[ri][1]=zz; }

  for (int ks=0; ks<16; ++ks){
    int koff = (ks*64 + lg*16) ^ (int)swzL;
    bf16x8 a0 = *(const bf16x8*)(pa0 + koff);
    bf16x8 a1 = *(const bf16x8*)(pa1 + koff);
    int kw = ks*32;
    #pragma unroll
    for (int ct=0; ct<2; ++ct){
      bf16x8 b = *(const bf16x8*)(wg0 + ct*16*512 + kw);
      accg[0][ct] = __builtin_amdgcn_mfma_f32_16x16x32_bf16(a0, b, accg[0][ct], 0,0,0);
      accg[1][ct] = __builtin_amdgcn_mfma_f32_16x16x32_bf16(a1, b, accg[1][ct], 0,0,0);
    }
  }

  float bgv[2], bcv[2];
  #pragma unroll
  for (int ct=0;ct<2;ct++){ int c = wc*32+ct*16+l15; bgv[ct]=bg[c]; bcv[ct]=bc[c]; }
  #pragma unroll
  for (int ri=0;ri<2;ri++)
    #pragma unroll
    for (int ct=0;ct<2;ct++)
      #pragma unroll
      for (int j=0;j<4;j++)
        accg[ri][ct][j] = 1.f/(1.f + __expf(-(accg[ri][ct][j] + bgv[ct])));

  for (int ks=0; ks<16; ++ks){
    int koff = (ks*64 + lg*16) ^ (int)swzL;
    bf16x8 a0 = *(const bf16x8*)(pa0 + koff);
    bf16x8 a1 = *(const bf16x8*)(pa1 + koff);
    int kw = ks*32;
    #pragma unroll
    for (int ct=0; ct<2; ++ct){
      bf16x8 b = *(const bf16x8*)(wc0 + ct*16*512 + kw);
      accc[0][ct] = __builtin_amdgcn_mfma_f32_16x16x32_bf16(a0, b, accc[0][ct], 0,0,0);
      accc[1][ct] = __builtin_amdgcn_mfma_f32_16x16x32_bf16(a1, b, accc[1][ct], 0,0,0);
    }
  }

  #pragma unroll
  for (int ct=0; ct<2; ++ct){
    #pragma unroll
    for (int ri=0; ri<2; ++ri){
      #pragma unroll
      for (int j=0;j<4;j++){
        int row = wr*32 + ri*16 + lg*4 + j;
        int col = wc*32 + ct*16 + l15;
        int e = e0 + row;
        float prevv = prevn[(size_t)e*DD + col];
        float fr = accg[ri][ct][j];
        float cand = fmaxf(accc[ri][ct][j] + bcv[ct], 0.f);
        out[(size_t)e*DD + col] = fr*prevv + (1.f-fr)*cand;
      }
    }
  }
}

extern "C" void kernel_launch(void* const* d_in, const int* in_sizes, int n_in,
                              void* d_out, int out_size, void* d_ws, size_t ws_size,
                              hipStream_t stream){
  const float* expr = (const float*)d_in[0];
  const float* sym  = (const float*)d_in[1];
  const float* prevn= (const float*)d_in[2];
  const float* Wg1 = (const float*)d_in[3];
  const float* bg1 = (const float*)d_in[4];
  const float* Wc1 = (const float*)d_in[5];
  const float* bc1 = (const float*)d_in[6];
  const float* Wg2 = (const float*)d_in[7];
  const float* bg2 = (const float*)d_in[8];
  const float* Wc2 = (const float*)d_in[9];
  const float* bc2 = (const float*)d_in[10];
  const int* aei = (const int*)d_in[11];
  const int* ati = (const int*)d_in[12];
  const int* asi = (const int*)d_in[13];
  float* outp = (float*)d_out;

  char* wsb = (char*)d_ws;
  int* winner = (int*)(wsb + WS_WINNER);
  char* wtsw = wsb + WS_WTSW;
  unsigned short* wtlin = (unsigned short*)(wsb + WS_WTLIN);
  unsigned short* symgc = (unsigned short*)(wsb + WS_SYMGC);

  hipMemsetAsync(winner, 0xFF, NSLOT*sizeof(int), stream);
  k_wt<<<256, 256, 0, stream>>>(Wg1, Wc1, Wg2, Wc2, wtsw, wtlin);
  k_winner<<<NAPP/256, 256, 0, stream>>>(aei, ati, winner);
  k_syms<<<NSYMP/64, 512, 0, stream>>>(sym, wtsw, symgc);
  k_gate1<<<NSLOT/64, 512, 0, stream>>>(expr, wtsw, bg1, bc1, winner, asi, symgc, outp);
  k_gate2<<<NE/64, 1024, 0, stream>>>(prevn, outp, bg2, bc2,
                                      wtlin + 262144, wtlin + 393216, outp);
}